// Round 5
// baseline (1931.320 us; speedup 1.0000x reference)
//
#include <hip/hip_runtime.h>

// KiloNeRF grouped tiny-MLP — round 9 (resubmit; round-4 bench was a broker
// GPUAcquisitionTimeout, kernel never ran): lane-per-point, STATIC arrays.
//
// Round-7/8 post-mortem: FETCH 94MB / WRITE 81MB, identical across the
// sincosf->sinf/cosf change => trig was not the culprit. The real one is
// rule #20: "#pragma unroll 2" in matvec_split left act[ii] runtime-indexed,
// so h[16]/g[16]/f[16] (and v[k] in the rgb head) lived in SCRATCH (= HBM).
// Every matvec paid a global-latency round trip per element -> VALUBusy 7.6%.
// Round-9: FULL unroll of the split-matvec and rgb-head loops so every array
// access is compile-time static (SROA -> registers). __launch_bounds__(64,3)
// caps VGPR ~168 to prevent round-6-style load-hoist ballooning while leaving
// headroom over 128 so nothing is force-spilled.
// Decomposition unchanged: wave=(expert, 32-pt chunk), lane=(point, half),
// partner-half scalars via __shfl_xor(...,32), weights broadcast-loaded from
// global in original [i][o] layout; no LDS, no __syncthreads.

// ---- workspace layout (ints) ----
#define WS_COUNTS 0
#define WS_OFFSETS 4096
#define WS_CURSOR 8192
#define WS_ORDER 12288

__device__ __forceinline__ int expert_id(float px, float py, float pz) {
    float nx = (px - (-1.5f)) / 3.0f;
    float ny = (py - (-1.5f)) / 3.0f;
    float nz = (pz - (-1.5f)) / 3.0f;
    float sx = fminf(fmaxf(nx * 16.0f, 0.0f), 15.0f);
    float sy = fminf(fmaxf(ny * 16.0f, 0.0f), 15.0f);
    float sz = fminf(fmaxf(nz * 16.0f, 0.0f), 15.0f);
    return (int)sx * 256 + (int)sy * 16 + (int)sz;
}

// acc[0..15] += x * row[0..15]   (row 16B-aligned, uniform per half)
__device__ __forceinline__ void fma16(float acc[16], const float* __restrict__ row,
                                      float x) {
#pragma unroll
    for (int k = 0; k < 16; k += 4) {
        const float4 w = *(const float4*)(row + k);
        acc[k + 0] = fmaf(x, w.x, acc[k + 0]);
        acc[k + 1] = fmaf(x, w.y, acc[k + 1]);
        acc[k + 2] = fmaf(x, w.z, acc[k + 2]);
        acc[k + 3] = fmaf(x, w.w, acc[k + 3]);
    }
}

__device__ __forceinline__ void ld_bias16(float acc[16], const float* __restrict__ b) {
#pragma unroll
    for (int k = 0; k < 16; k += 4) {
        const float4 v = *(const float4*)(b + k);
        acc[k + 0] = v.x; acc[k + 1] = v.y; acc[k + 2] = v.z; acc[k + 3] = v.w;
    }
}

// acc[ob..ob+15] += sum_{i=0..31} h[i] * W[i][ob..ob+15], where this lane holds
// act[ii] = h[ob+ii] and the partner lane (lane^32) holds h[(ob^16)+ii].
// FULLY unrolled: act[] indices must be compile-time constants (rule #20).
__device__ __forceinline__ void matvec_split(float acc[16], const float* __restrict__ Wexp,
                                             const float act[16], int ob) {
    const float* __restrict__ Wself = Wexp + (ob) * 32 + ob;
    const float* __restrict__ Woth  = Wexp + (ob ^ 16) * 32 + ob;
#pragma unroll
    for (int ii = 0; ii < 16; ++ii) {
        const float hs = act[ii];
        const float ho = __shfl_xor(hs, 32, 64);
        fma16(acc, Wself + ii * 32, hs);
        fma16(acc, Woth + ii * 32, ho);
    }
}

// ---------------- pass A: histogram ----------------
__global__ __launch_bounds__(256) void hist_kernel(const float* __restrict__ pts,
                                                   int* __restrict__ counts, int n) {
    int i = blockIdx.x * 256 + threadIdx.x;
    if (i < n) {
        int e = expert_id(pts[3 * i + 0], pts[3 * i + 1], pts[3 * i + 2]);
        atomicAdd(&counts[e], 1);
    }
}

// ---------------- pass B: exclusive scan of 4096 counts (1 block) ----------
__global__ __launch_bounds__(256) void scan_kernel(const int* __restrict__ counts,
                                                   int* __restrict__ offsets,
                                                   int* __restrict__ cursor) {
    const int tid = threadIdx.x;
    const int lane = tid & 63, wave = tid >> 6;
    const int base = tid * 16;
    int c[16], loc[16], sum = 0;
#pragma unroll
    for (int j = 0; j < 16; ++j) c[j] = counts[base + j];
#pragma unroll
    for (int j = 0; j < 16; ++j) { loc[j] = sum; sum += c[j]; }
    int v = sum;
#pragma unroll
    for (int off = 1; off <= 32; off <<= 1) {
        int u = __shfl_up(v, off, 64);
        if (lane >= off) v += u;
    }
    __shared__ int wtot[4];
    if (lane == 63) wtot[wave] = v;
    __syncthreads();
    int wbase = 0;
    for (int w = 0; w < wave; ++w) wbase += wtot[w];
    const int excl = wbase + v - sum;
#pragma unroll
    for (int j = 0; j < 16; ++j) {
        int o = excl + loc[j];
        offsets[base + j] = o;
        cursor[base + j] = o;
    }
}

// ---------------- pass C: scatter point ids into buckets ----------------
__global__ __launch_bounds__(256) void scatter_kernel(const float* __restrict__ pts,
                                                      int* __restrict__ cursor,
                                                      int* __restrict__ order, int n) {
    int i = blockIdx.x * 256 + threadIdx.x;
    if (i < n) {
        int e = expert_id(pts[3 * i + 0], pts[3 * i + 1], pts[3 * i + 2]);
        int pos = atomicAdd(&cursor[e], 1);
        order[pos] = i;
    }
}

// ---------------- pass D: wave per (expert, 32-pt chunk), lane = (pt, half) ----
__global__ __launch_bounds__(64, 3) void expert_mlp_kernel(
    const float* __restrict__ pts, const float* __restrict__ viewdirs,
    const float* __restrict__ W1, const float* __restrict__ b1,
    const float* __restrict__ W2, const float* __restrict__ b2,
    const float* __restrict__ Wf, const float* __restrict__ bfc,
    const float* __restrict__ Wsig, const float* __restrict__ bsig,
    const float* __restrict__ Wv, const float* __restrict__ bv,
    const float* __restrict__ Wrgb, const float* __restrict__ brgb,
    const int* __restrict__ counts, const int* __restrict__ offsets,
    const int* __restrict__ order,
    float* __restrict__ out_rgb, float* __restrict__ out_sigma, int samples) {

    const int e = blockIdx.x >> 1;
    const int chunk = blockIdx.x & 1;
    const int cnt = counts[e];
    if (chunk * 32 >= cnt) return;
    const int start = offsets[e];

    const int lane = threadIdx.x;
    const int pidx = lane & 31;      // point slot within chunk
    const int hi = lane >> 5;        // output half
    const int ob = hi << 4;          // output base (0 or 16)

    // samples is a power of two (64) -> shift; keep a uniform fallback
    const bool pow2 = (samples & (samples - 1)) == 0;
    const int sh = 31 - __clz(samples);

    const float* __restrict__ W1o = W1 + (size_t)e * 2016 + ob;   // [63][32]
    const float* __restrict__ W2e = W2 + (size_t)e * 1024;        // [32][32]
    const float* __restrict__ Wfe = Wf + (size_t)e * 1024;        // [32][32]
    const float* __restrict__ Wve = Wv + (size_t)e * 1888;        // [59][32]
    const float* __restrict__ Wvo = Wve + ob;
    const float* __restrict__ Wse = Wsig + (size_t)e * 32;        // [32]
    const float* __restrict__ Wre = Wrgb + (size_t)e * 96;        // [32][3]

    for (int s0 = chunk * 32; s0 < cnt; s0 += 64) {
        const int s = s0 + pidx;
        const bool live = (s < cnt);
        const bool act_store = live && (hi == 0);
        const int pt = order[start + (live ? s : (cnt - 1))];

        const float px = pts[3 * pt + 0];
        const float py = pts[3 * pt + 1];
        const float pz = pts[3 * pt + 2];
        const int ray = pow2 ? (pt >> sh) : (pt / samples);
        const float dx = viewdirs[3 * ray + 0];
        const float dy = viewdirs[3 * ray + 1];
        const float dz = viewdirs[3 * ray + 2];

        // ---- layer 1: 63 -> 32 (this half's 16), posenc(p) on the fly ----
        float acc[16];
        ld_bias16(acc, b1 + e * 32 + ob);
        fma16(acc, W1o + 0 * 32, px);
        fma16(acc, W1o + 1 * 32, py);
        fma16(acc, W1o + 2 * 32, pz);
        {
            float tx = px, ty = py, tz = pz;   // exact *2 doubling == 2^l * x
#pragma unroll 1
            for (int l = 0; l < 10; ++l) {
                const float sx = sinf(tx), cx = cosf(tx);
                const float sy = sinf(ty), cy = cosf(ty);
                const float sz = sinf(tz), cz = cosf(tz);
                const float* r = W1o + (3 + 6 * l) * 32;
                fma16(acc, r + 0 * 32, sx);
                fma16(acc, r + 1 * 32, sy);
                fma16(acc, r + 2 * 32, sz);
                fma16(acc, r + 3 * 32, cx);
                fma16(acc, r + 4 * 32, cy);
                fma16(acc, r + 5 * 32, cz);
                tx += tx; ty += ty; tz += tz;
            }
        }
        float h[16];
#pragma unroll
        for (int k = 0; k < 16; ++k) h[k] = fmaxf(acc[k], 0.f);

        // ---- layer 2: 32 -> 32 ----
        float acc2[16];
        ld_bias16(acc2, b2 + e * 32 + ob);
        matvec_split(acc2, W2e, h, ob);
        float g[16];
#pragma unroll
        for (int k = 0; k < 16; ++k) g[k] = fmaxf(acc2[k], 0.f);

        // ---- sigma head: half-partial dot + one shfl-add ----
        {
            float sg = 0.f;
#pragma unroll
            for (int q = 0; q < 4; ++q) {
                const float4 w = *(const float4*)(Wse + ob + 4 * q);
                sg = fmaf(g[4 * q + 0], w.x, sg);
                sg = fmaf(g[4 * q + 1], w.y, sg);
                sg = fmaf(g[4 * q + 2], w.z, sg);
                sg = fmaf(g[4 * q + 3], w.w, sg);
            }
            sg += __shfl_xor(sg, 32, 64);
            if (act_store) out_sigma[pt] = sg + bsig[e];
        }

        // ---- feat: 32 -> 32, no relu ----
        float f[16];
        ld_bias16(f, bfc + e * 32 + ob);
        matvec_split(f, Wfe, g, ob);

        // ---- view layer: 59 -> 32 (inputs = [feat(32, split), posenc(d)]) ----
        float accv[16];
        ld_bias16(accv, bv + e * 32 + ob);
        matvec_split(accv, Wve, f, ob);
        fma16(accv, Wvo + 32 * 32, dx);
        fma16(accv, Wvo + 33 * 32, dy);
        fma16(accv, Wvo + 34 * 32, dz);
        {
            float tx = dx, ty = dy, tz = dz;
#pragma unroll 1
            for (int l = 0; l < 4; ++l) {
                const float sx = sinf(tx), cx = cosf(tx);
                const float sy = sinf(ty), cy = cosf(ty);
                const float sz = sinf(tz), cz = cosf(tz);
                const float* r = Wvo + (35 + 6 * l) * 32;
                fma16(accv, r + 0 * 32, sx);
                fma16(accv, r + 1 * 32, sy);
                fma16(accv, r + 2 * 32, sz);
                fma16(accv, r + 3 * 32, cx);
                fma16(accv, r + 4 * 32, cy);
                fma16(accv, r + 5 * 32, cz);
                tx += tx; ty += ty; tz += tz;
            }
        }
        float v[16];
#pragma unroll
        for (int k = 0; k < 16; ++k) v[k] = fmaxf(accv[k], 0.f);

        // ---- rgb head: 3 half-partial dots + shfl-adds (FULL unroll) ----
        {
            float r0 = 0.f, r1 = 0.f, r2 = 0.f;
#pragma unroll
            for (int k = 0; k < 16; ++k) {
                const float* wr = Wre + (ob + k) * 3;
                r0 = fmaf(v[k], wr[0], r0);
                r1 = fmaf(v[k], wr[1], r1);
                r2 = fmaf(v[k], wr[2], r2);
            }
            r0 += __shfl_xor(r0, 32, 64);
            r1 += __shfl_xor(r1, 32, 64);
            r2 += __shfl_xor(r2, 32, 64);
            if (act_store) {
                out_rgb[3 * pt + 0] = r0 + brgb[3 * e + 0];
                out_rgb[3 * pt + 1] = r1 + brgb[3 * e + 1];
                out_rgb[3 * pt + 2] = r2 + brgb[3 * e + 2];
            }
        }
    }
}

extern "C" void kernel_launch(void* const* d_in, const int* in_sizes, int n_in,
                              void* d_out, int out_size, void* d_ws, size_t ws_size,
                              hipStream_t stream) {
    const float* pts      = (const float*)d_in[0];
    const float* viewdirs = (const float*)d_in[1];
    const float* W1   = (const float*)d_in[2];
    const float* b1   = (const float*)d_in[3];
    const float* W2   = (const float*)d_in[4];
    const float* b2   = (const float*)d_in[5];
    const float* Wf   = (const float*)d_in[6];
    const float* bfc  = (const float*)d_in[7];
    const float* Wsig = (const float*)d_in[8];
    const float* bsig = (const float*)d_in[9];
    const float* Wv   = (const float*)d_in[10];
    const float* bv   = (const float*)d_in[11];
    const float* Wrgb = (const float*)d_in[12];
    const float* brgb = (const float*)d_in[13];

    const int n = in_sizes[0] / 3;          // 65536 points
    const int n_rays = in_sizes[1] / 3;     // 1024 rays
    const int samples = n / n_rays;         // 64 samples/ray

    float* out_rgb = (float*)d_out;
    float* out_sigma = out_rgb + (size_t)n * 3;

    int* ws = (int*)d_ws;
    int* counts = ws + WS_COUNTS;
    int* offsets = ws + WS_OFFSETS;
    int* cursor = ws + WS_CURSOR;
    int* order = ws + WS_ORDER;

    hipMemsetAsync(counts, 0, 4096 * sizeof(int), stream);
    hist_kernel<<<(n + 255) / 256, 256, 0, stream>>>(pts, counts, n);
    scan_kernel<<<1, 256, 0, stream>>>(counts, offsets, cursor);
    scatter_kernel<<<(n + 255) / 256, 256, 0, stream>>>(pts, cursor, order, n);
    expert_mlp_kernel<<<4096 * 2, 64, 0, stream>>>(
        pts, viewdirs, W1, b1, W2, b2, Wf, bfc, Wsig, bsig, Wv, bv, Wrgb, brgb,
        counts, offsets, order, out_rgb, out_sigma, samples);
}

// Round 6
// 467.403 us; speedup vs baseline: 4.1320x; 4.1320x over previous
//
#include <hip/hip_runtime.h>

// KiloNeRF grouped tiny-MLP — round 10: thread-per-point, LDS activations.
//
// R7/8: rolled matvec + register-array activations -> runtime index -> SCRATCH
//       (FETCH 94MB/WRITE 81MB, VALUBusy 7.6%).
// R9:   full unroll + launch_bounds(64,3) -> allocator spilled wholesale
//       (VGPR 84, WRITE 1.88GB, VALUBusy 1.7%).
// Root cause both times: activations in register arrays indexed by the
// reduction loop. Round-10: activations live in a per-thread PADDED LDS row
// (stride 33 -> conflict-free; runtime indexing legal in memory). Block =
// expert, 64 threads = 1 wave, thread-per-point: acc[32] indexed only by the
// statically-unrolled OUTPUT dim; reduction loops stay ROLLED (unroll 2,
// bounded in-flight loads). Weights are wave-uniform broadcast loads from
// global. Single 8.4KB LDS buffer reused across layers (each thread fully
// reads its row before overwriting it; same-wave program order). No
// __syncthreads, no shuffles, no launch_bounds 2nd arg.

// ---- workspace layout (ints) ----
#define WS_COUNTS 0
#define WS_OFFSETS 4096
#define WS_CURSOR 8192
#define WS_ORDER 12288

#define PAD 33

__device__ __forceinline__ int expert_id(float px, float py, float pz) {
    float nx = (px - (-1.5f)) / 3.0f;
    float ny = (py - (-1.5f)) / 3.0f;
    float nz = (pz - (-1.5f)) / 3.0f;
    float sx = fminf(fmaxf(nx * 16.0f, 0.0f), 15.0f);
    float sy = fminf(fmaxf(ny * 16.0f, 0.0f), 15.0f);
    float sz = fminf(fmaxf(nz * 16.0f, 0.0f), 15.0f);
    return (int)sx * 256 + (int)sy * 16 + (int)sz;
}

// acc[0..31] += x * row[0..31]   (row 16B-aligned, wave-uniform broadcast)
__device__ __forceinline__ void fmarow32(float acc[32], const float* __restrict__ row,
                                         float x) {
#pragma unroll
    for (int k = 0; k < 32; k += 4) {
        const float4 w = *(const float4*)(row + k);
        acc[k + 0] = fmaf(x, w.x, acc[k + 0]);
        acc[k + 1] = fmaf(x, w.y, acc[k + 1]);
        acc[k + 2] = fmaf(x, w.z, acc[k + 2]);
        acc[k + 3] = fmaf(x, w.w, acc[k + 3]);
    }
}

__device__ __forceinline__ void ld_bias32(float acc[32], const float* __restrict__ b) {
#pragma unroll
    for (int k = 0; k < 32; k += 4) {
        const float4 v = *(const float4*)(b + k);
        acc[k + 0] = v.x; acc[k + 1] = v.y; acc[k + 2] = v.z; acc[k + 3] = v.w;
    }
}

// ---------------- pass A: histogram ----------------
__global__ __launch_bounds__(256) void hist_kernel(const float* __restrict__ pts,
                                                   int* __restrict__ counts, int n) {
    int i = blockIdx.x * 256 + threadIdx.x;
    if (i < n) {
        int e = expert_id(pts[3 * i + 0], pts[3 * i + 1], pts[3 * i + 2]);
        atomicAdd(&counts[e], 1);
    }
}

// ---------------- pass B: exclusive scan of 4096 counts (1 block) ----------
__global__ __launch_bounds__(256) void scan_kernel(const int* __restrict__ counts,
                                                   int* __restrict__ offsets,
                                                   int* __restrict__ cursor) {
    const int tid = threadIdx.x;
    const int lane = tid & 63, wave = tid >> 6;
    const int base = tid * 16;
    int c[16], loc[16], sum = 0;
#pragma unroll
    for (int j = 0; j < 16; ++j) c[j] = counts[base + j];
#pragma unroll
    for (int j = 0; j < 16; ++j) { loc[j] = sum; sum += c[j]; }
    int v = sum;
#pragma unroll
    for (int off = 1; off <= 32; off <<= 1) {
        int u = __shfl_up(v, off, 64);
        if (lane >= off) v += u;
    }
    __shared__ int wtot[4];
    if (lane == 63) wtot[wave] = v;
    __syncthreads();
    int wbase = 0;
    for (int w = 0; w < wave; ++w) wbase += wtot[w];
    const int excl = wbase + v - sum;
#pragma unroll
    for (int j = 0; j < 16; ++j) {
        int o = excl + loc[j];
        offsets[base + j] = o;
        cursor[base + j] = o;
    }
}

// ---------------- pass C: scatter point ids into buckets ----------------
__global__ __launch_bounds__(256) void scatter_kernel(const float* __restrict__ pts,
                                                      int* __restrict__ cursor,
                                                      int* __restrict__ order, int n) {
    int i = blockIdx.x * 256 + threadIdx.x;
    if (i < n) {
        int e = expert_id(pts[3 * i + 0], pts[3 * i + 1], pts[3 * i + 2]);
        int pos = atomicAdd(&cursor[e], 1);
        order[pos] = i;
    }
}

// ---------------- pass D: block = (expert, 64-pt chunk), thread = point ------
__global__ void expert_mlp_kernel(
    const float* __restrict__ pts, const float* __restrict__ viewdirs,
    const float* __restrict__ W1, const float* __restrict__ b1,
    const float* __restrict__ W2, const float* __restrict__ b2,
    const float* __restrict__ Wf, const float* __restrict__ bfc,
    const float* __restrict__ Wsig, const float* __restrict__ bsig,
    const float* __restrict__ Wv, const float* __restrict__ bv,
    const float* __restrict__ Wrgb, const float* __restrict__ brgb,
    const int* __restrict__ counts, const int* __restrict__ offsets,
    const int* __restrict__ order,
    float* __restrict__ out_rgb, float* __restrict__ out_sigma, int samples) {

    const int e = blockIdx.x >> 1;
    const int chunk = blockIdx.x & 1;
    const int cnt = counts[e];
    if (chunk * 64 >= cnt) return;
    const int start = offsets[e];
    const int tid = threadIdx.x;           // 0..63, one wave

    __shared__ float act[64 * PAD];        // per-thread padded activation row
    float* __restrict__ my = act + tid * PAD;

    const bool pow2 = (samples & (samples - 1)) == 0;
    const int sh = 31 - __clz(samples);

    const float* __restrict__ W1e = W1 + (size_t)e * 2016;   // [63][32]
    const float* __restrict__ W2e = W2 + (size_t)e * 1024;   // [32][32]
    const float* __restrict__ Wfe = Wf + (size_t)e * 1024;   // [32][32]
    const float* __restrict__ Wve = Wv + (size_t)e * 1888;   // [59][32]
    const float* __restrict__ Wse = Wsig + (size_t)e * 32;   // [32]
    const float* __restrict__ Wre = Wrgb + (size_t)e * 96;   // [32][3]

    for (int s0 = chunk * 64; s0 < cnt; s0 += 128) {
        const int s = s0 + tid;
        const bool live = (s < cnt);
        const int pt = order[start + (live ? s : (cnt - 1))];

        const float px = pts[3 * pt + 0];
        const float py = pts[3 * pt + 1];
        const float pz = pts[3 * pt + 2];
        const int ray = pow2 ? (pt >> sh) : (pt / samples);
        const float dx = viewdirs[3 * ray + 0];
        const float dy = viewdirs[3 * ray + 1];
        const float dz = viewdirs[3 * ray + 2];

        // ---- layer 1: 63 -> 32, posenc(p) generated on the fly ----
        float acc[32];
        ld_bias32(acc, b1 + e * 32);
        fmarow32(acc, W1e + 0 * 32, px);
        fmarow32(acc, W1e + 1 * 32, py);
        fmarow32(acc, W1e + 2 * 32, pz);
        {
            float tx = px, ty = py, tz = pz;   // exact *2 doubling == 2^l * x
#pragma unroll 1
            for (int l = 0; l < 10; ++l) {
                const float sx = sinf(tx), cx = cosf(tx);
                const float sy = sinf(ty), cy = cosf(ty);
                const float sz = sinf(tz), cz = cosf(tz);
                const float* r = W1e + (3 + 6 * l) * 32;
                fmarow32(acc, r + 0 * 32, sx);
                fmarow32(acc, r + 1 * 32, sy);
                fmarow32(acc, r + 2 * 32, sz);
                __builtin_amdgcn_sched_barrier(0);   // cap in-flight loads
                fmarow32(acc, r + 3 * 32, cx);
                fmarow32(acc, r + 4 * 32, cy);
                fmarow32(acc, r + 5 * 32, cz);
                tx += tx; ty += ty; tz += tz;
            }
        }
#pragma unroll
        for (int k = 0; k < 32; ++k) my[k] = fmaxf(acc[k], 0.f);   // h -> LDS

        // ---- layer 2: 32 -> 32 (+relu) ----
        float acc2[32];
        ld_bias32(acc2, b2 + e * 32);
#pragma unroll 2
        for (int i = 0; i < 32; ++i) fmarow32(acc2, W2e + i * 32, my[i]);
#pragma unroll
        for (int k = 0; k < 32; ++k) my[k] = fmaxf(acc2[k], 0.f);  // g -> LDS

        // ---- sigma head: dot(g, Wsig) + bsig ----
        {
            float sg = 0.f;
#pragma unroll 4
            for (int i = 0; i < 32; ++i) sg = fmaf(my[i], Wse[i], sg);
            if (live) out_sigma[pt] = sg + bsig[e];
        }

        // ---- feat: 32 -> 32, no relu ----
        float accf[32];
        ld_bias32(accf, bfc + e * 32);
#pragma unroll 2
        for (int i = 0; i < 32; ++i) fmarow32(accf, Wfe + i * 32, my[i]);
#pragma unroll
        for (int k = 0; k < 32; ++k) my[k] = accf[k];              // feat -> LDS

        // ---- view layer: 59 -> 32 (+relu): [feat(32), posenc(d)(27)] ----
        float accv[32];
        ld_bias32(accv, bv + e * 32);
#pragma unroll 2
        for (int i = 0; i < 32; ++i) fmarow32(accv, Wve + i * 32, my[i]);
        fmarow32(accv, Wve + 32 * 32, dx);
        fmarow32(accv, Wve + 33 * 32, dy);
        fmarow32(accv, Wve + 34 * 32, dz);
        {
            float tx = dx, ty = dy, tz = dz;
#pragma unroll 1
            for (int l = 0; l < 4; ++l) {
                const float sx = sinf(tx), cx = cosf(tx);
                const float sy = sinf(ty), cy = cosf(ty);
                const float sz = sinf(tz), cz = cosf(tz);
                const float* r = Wve + (35 + 6 * l) * 32;
                fmarow32(accv, r + 0 * 32, sx);
                fmarow32(accv, r + 1 * 32, sy);
                fmarow32(accv, r + 2 * 32, sz);
                __builtin_amdgcn_sched_barrier(0);
                fmarow32(accv, r + 3 * 32, cx);
                fmarow32(accv, r + 4 * 32, cy);
                fmarow32(accv, r + 5 * 32, cz);
                tx += tx; ty += ty; tz += tz;
            }
        }
#pragma unroll
        for (int k = 0; k < 32; ++k) my[k] = fmaxf(accv[k], 0.f);  // hv -> LDS

        // ---- rgb head: 3 dots over 32 ----
        {
            float r0 = 0.f, r1 = 0.f, r2 = 0.f;
#pragma unroll 4
            for (int i = 0; i < 32; ++i) {
                const float vv = my[i];
                const float* wr = Wre + i * 3;
                r0 = fmaf(vv, wr[0], r0);
                r1 = fmaf(vv, wr[1], r1);
                r2 = fmaf(vv, wr[2], r2);
            }
            if (live) {
                out_rgb[3 * pt + 0] = r0 + brgb[3 * e + 0];
                out_rgb[3 * pt + 1] = r1 + brgb[3 * e + 1];
                out_rgb[3 * pt + 2] = r2 + brgb[3 * e + 2];
            }
        }
    }
}

extern "C" void kernel_launch(void* const* d_in, const int* in_sizes, int n_in,
                              void* d_out, int out_size, void* d_ws, size_t ws_size,
                              hipStream_t stream) {
    const float* pts      = (const float*)d_in[0];
    const float* viewdirs = (const float*)d_in[1];
    const float* W1   = (const float*)d_in[2];
    const float* b1   = (const float*)d_in[3];
    const float* W2   = (const float*)d_in[4];
    const float* b2   = (const float*)d_in[5];
    const float* Wf   = (const float*)d_in[6];
    const float* bfc  = (const float*)d_in[7];
    const float* Wsig = (const float*)d_in[8];
    const float* bsig = (const float*)d_in[9];
    const float* Wv   = (const float*)d_in[10];
    const float* bv   = (const float*)d_in[11];
    const float* Wrgb = (const float*)d_in[12];
    const float* brgb = (const float*)d_in[13];

    const int n = in_sizes[0] / 3;          // 65536 points
    const int n_rays = in_sizes[1] / 3;     // 1024 rays
    const int samples = n / n_rays;         // 64 samples/ray

    float* out_rgb = (float*)d_out;
    float* out_sigma = out_rgb + (size_t)n * 3;

    int* ws = (int*)d_ws;
    int* counts = ws + WS_COUNTS;
    int* offsets = ws + WS_OFFSETS;
    int* cursor = ws + WS_CURSOR;
    int* order = ws + WS_ORDER;

    hipMemsetAsync(counts, 0, 4096 * sizeof(int), stream);
    hist_kernel<<<(n + 255) / 256, 256, 0, stream>>>(pts, counts, n);
    scan_kernel<<<1, 256, 0, stream>>>(counts, offsets, cursor);
    scatter_kernel<<<(n + 255) / 256, 256, 0, stream>>>(pts, cursor, order, n);
    expert_mlp_kernel<<<4096 * 2, 64, 0, stream>>>(
        pts, viewdirs, W1, b1, W2, b2, Wf, bfc, Wsig, bsig, Wv, bv, Wrgb, brgb,
        counts, offsets, order, out_rgb, out_sigma, samples);
}

// Round 7
// 368.454 us; speedup vs baseline: 5.2417x; 1.2686x over previous
//
#include <hip/hip_runtime.h>

// KiloNeRF grouped tiny-MLP — round 11: LDS-staged weights + LDS activations.
//
// R10 post-mortem: scratch eliminated (WRITE 3.5MB) but 325us at VALUBusy
// 12.5% / HBM 4% -> latency-bound on ~1500 wave-uniform global weight loads
// per point-iteration, exposed in dependent batches with only ~2.4 waves/SIMD
// of TLP. R11: block = expert (64 thr, 1 wave). Stage the expert's whole
// 24.8KB weight slab into LDS via two-phase float4 staging (all loads issue,
// then all ds_writes -> ONE pipelined HBM round trip), then compute reads
// weight rows as broadcast ds_read_b128 (conflict-free) and activations from
// the stride-33 padded LDS row (runtime indexing legal in memory; acc[32]
// indexed only by statically-unrolled output dim). One block per expert ->
// each weight byte fetched once (FETCH ~55MB). No __syncthreads (same-wave
// DS ordering is program order - proven in round 5). No launch_bounds cap.

// ---- workspace layout (ints) ----
#define WS_COUNTS 0
#define WS_OFFSETS 4096
#define WS_CURSOR 8192
#define WS_ORDER 12288

#define PAD 33

// ---- LDS weight slab offsets (floats, all 16B-aligned) ----
#define L_W1 0        // [63][32]
#define L_W2 2016     // [32][32]
#define L_WF 3040     // [32][32]
#define L_WV 4064     // [59][32]
#define L_WS 5952     // [32]
#define L_WR 5984     // [32][3]
#define L_B1 6080
#define L_B2 6112
#define L_BF 6144
#define L_BV 6176
#define L_BSR 6208    // [0]=bsig, [1..3]=brgb
#define L_TOT 6212

__device__ __forceinline__ int expert_id(float px, float py, float pz) {
    float nx = (px - (-1.5f)) / 3.0f;
    float ny = (py - (-1.5f)) / 3.0f;
    float nz = (pz - (-1.5f)) / 3.0f;
    float sx = fminf(fmaxf(nx * 16.0f, 0.0f), 15.0f);
    float sy = fminf(fmaxf(ny * 16.0f, 0.0f), 15.0f);
    float sz = fminf(fmaxf(nz * 16.0f, 0.0f), 15.0f);
    return (int)sx * 256 + (int)sy * 16 + (int)sz;
}

// two-phase staging: issue all global loads into regs, then all LDS writes.
// buf[] statically indexed (rule #20 safe).
template <int N4>
__device__ __forceinline__ void stage4(float* dst, const float* __restrict__ src,
                                       int tid) {
    constexpr int ITER = (N4 + 63) / 64;
    float4 buf[ITER];
#pragma unroll
    for (int j = 0; j < ITER; ++j) {
        const int t = j * 64 + tid;
        if (t < N4) buf[j] = ((const float4*)src)[t];
    }
#pragma unroll
    for (int j = 0; j < ITER; ++j) {
        const int t = j * 64 + tid;
        if (t < N4) ((float4*)dst)[t] = buf[j];
    }
}

// acc[0..31] += x * row[0..31]   (row = LDS, wave-uniform -> broadcast b128)
__device__ __forceinline__ void fmarow32(float acc[32], const float* row, float x) {
#pragma unroll
    for (int k = 0; k < 32; k += 4) {
        const float4 w = *(const float4*)(row + k);
        acc[k + 0] = fmaf(x, w.x, acc[k + 0]);
        acc[k + 1] = fmaf(x, w.y, acc[k + 1]);
        acc[k + 2] = fmaf(x, w.z, acc[k + 2]);
        acc[k + 3] = fmaf(x, w.w, acc[k + 3]);
    }
}

__device__ __forceinline__ void ld_bias32(float acc[32], const float* b) {
#pragma unroll
    for (int k = 0; k < 32; k += 4) {
        const float4 v = *(const float4*)(b + k);
        acc[k + 0] = v.x; acc[k + 1] = v.y; acc[k + 2] = v.z; acc[k + 3] = v.w;
    }
}

// ---------------- pass A: histogram ----------------
__global__ __launch_bounds__(256) void hist_kernel(const float* __restrict__ pts,
                                                   int* __restrict__ counts, int n) {
    int i = blockIdx.x * 256 + threadIdx.x;
    if (i < n) {
        int e = expert_id(pts[3 * i + 0], pts[3 * i + 1], pts[3 * i + 2]);
        atomicAdd(&counts[e], 1);
    }
}

// ---------------- pass B: exclusive scan of 4096 counts (1 block) ----------
__global__ __launch_bounds__(256) void scan_kernel(const int* __restrict__ counts,
                                                   int* __restrict__ offsets,
                                                   int* __restrict__ cursor) {
    const int tid = threadIdx.x;
    const int lane = tid & 63, wave = tid >> 6;
    const int base = tid * 16;
    int c[16], loc[16], sum = 0;
#pragma unroll
    for (int j = 0; j < 16; ++j) c[j] = counts[base + j];
#pragma unroll
    for (int j = 0; j < 16; ++j) { loc[j] = sum; sum += c[j]; }
    int v = sum;
#pragma unroll
    for (int off = 1; off <= 32; off <<= 1) {
        int u = __shfl_up(v, off, 64);
        if (lane >= off) v += u;
    }
    __shared__ int wtot[4];
    if (lane == 63) wtot[wave] = v;
    __syncthreads();
    int wbase = 0;
    for (int w = 0; w < wave; ++w) wbase += wtot[w];
    const int excl = wbase + v - sum;
#pragma unroll
    for (int j = 0; j < 16; ++j) {
        int o = excl + loc[j];
        offsets[base + j] = o;
        cursor[base + j] = o;
    }
}

// ---------------- pass C: scatter point ids into buckets ----------------
__global__ __launch_bounds__(256) void scatter_kernel(const float* __restrict__ pts,
                                                      int* __restrict__ cursor,
                                                      int* __restrict__ order, int n) {
    int i = blockIdx.x * 256 + threadIdx.x;
    if (i < n) {
        int e = expert_id(pts[3 * i + 0], pts[3 * i + 1], pts[3 * i + 2]);
        int pos = atomicAdd(&cursor[e], 1);
        order[pos] = i;
    }
}

// ---------------- pass D: block = expert (1 wave), thread = point ----------
__global__ __launch_bounds__(64) void expert_mlp_kernel(
    const float* __restrict__ pts, const float* __restrict__ viewdirs,
    const float* __restrict__ W1, const float* __restrict__ b1,
    const float* __restrict__ W2, const float* __restrict__ b2,
    const float* __restrict__ Wf, const float* __restrict__ bfc,
    const float* __restrict__ Wsig, const float* __restrict__ bsig,
    const float* __restrict__ Wv, const float* __restrict__ bv,
    const float* __restrict__ Wrgb, const float* __restrict__ brgb,
    const int* __restrict__ counts, const int* __restrict__ offsets,
    const int* __restrict__ order,
    float* __restrict__ out_rgb, float* __restrict__ out_sigma, int samples) {

    const int e = blockIdx.x;
    const int cnt = counts[e];
    if (cnt == 0) return;
    const int start = offsets[e];
    const int tid = threadIdx.x;           // 0..63, one wave

    __shared__ float lw[L_TOT];            // staged weights (24.8 KB)
    __shared__ float act[64 * PAD];        // per-thread padded activation row
    float* my = act + tid * PAD;

    // ---- stage this expert's full weight slab (two-phase, pipelined) ----
    stage4<504>(lw + L_W1, W1 + (size_t)e * 2016, tid);
    stage4<256>(lw + L_W2, W2 + (size_t)e * 1024, tid);
    stage4<256>(lw + L_WF, Wf + (size_t)e * 1024, tid);
    stage4<472>(lw + L_WV, Wv + (size_t)e * 1888, tid);
    stage4<8>(lw + L_WS, Wsig + (size_t)e * 32, tid);
    stage4<24>(lw + L_WR, Wrgb + (size_t)e * 96, tid);
    stage4<8>(lw + L_B1, b1 + (size_t)e * 32, tid);
    stage4<8>(lw + L_B2, b2 + (size_t)e * 32, tid);
    stage4<8>(lw + L_BF, bfc + (size_t)e * 32, tid);
    stage4<8>(lw + L_BV, bv + (size_t)e * 32, tid);
    if (tid == 0) lw[L_BSR] = bsig[e];
    if (tid < 3) lw[L_BSR + 1 + tid] = brgb[3 * e + tid];
    // single wave: DS ops complete in program order -> no barrier needed

    const bool pow2 = (samples & (samples - 1)) == 0;
    const int sh = 31 - __clz(samples);

    for (int s0 = 0; s0 < cnt; s0 += 64) {
        const int s = s0 + tid;
        const bool live = (s < cnt);
        const int pt = order[start + (live ? s : (cnt - 1))];

        const float px = pts[3 * pt + 0];
        const float py = pts[3 * pt + 1];
        const float pz = pts[3 * pt + 2];
        const int ray = pow2 ? (pt >> sh) : (pt / samples);
        const float dx = viewdirs[3 * ray + 0];
        const float dy = viewdirs[3 * ray + 1];
        const float dz = viewdirs[3 * ray + 2];

        // ---- layer 1: 63 -> 32, posenc(p) generated on the fly ----
        float acc[32];
        ld_bias32(acc, lw + L_B1);
        fmarow32(acc, lw + L_W1 + 0 * 32, px);
        fmarow32(acc, lw + L_W1 + 1 * 32, py);
        fmarow32(acc, lw + L_W1 + 2 * 32, pz);
        {
            float tx = px, ty = py, tz = pz;   // exact *2 doubling == 2^l * x
#pragma unroll 1
            for (int l = 0; l < 10; ++l) {
                const float sx = sinf(tx), cx = cosf(tx);
                const float sy = sinf(ty), cy = cosf(ty);
                const float sz = sinf(tz), cz = cosf(tz);
                const float* r = lw + L_W1 + (3 + 6 * l) * 32;
                fmarow32(acc, r + 0 * 32, sx);
                fmarow32(acc, r + 1 * 32, sy);
                fmarow32(acc, r + 2 * 32, sz);
                fmarow32(acc, r + 3 * 32, cx);
                fmarow32(acc, r + 4 * 32, cy);
                fmarow32(acc, r + 5 * 32, cz);
                tx += tx; ty += ty; tz += tz;
            }
        }
#pragma unroll
        for (int k = 0; k < 32; ++k) my[k] = fmaxf(acc[k], 0.f);   // h -> LDS

        // ---- layer 2: 32 -> 32 (+relu) ----
        float acc2[32];
        ld_bias32(acc2, lw + L_B2);
#pragma unroll 2
        for (int i = 0; i < 32; ++i) fmarow32(acc2, lw + L_W2 + i * 32, my[i]);
#pragma unroll
        for (int k = 0; k < 32; ++k) my[k] = fmaxf(acc2[k], 0.f);  // g -> LDS

        // ---- sigma head: dot(g, Wsig) + bsig ----
        {
            float sg = 0.f;
#pragma unroll 4
            for (int i = 0; i < 32; ++i) sg = fmaf(my[i], lw[L_WS + i], sg);
            if (live) out_sigma[pt] = sg + lw[L_BSR];
        }

        // ---- feat: 32 -> 32, no relu ----
        float accf[32];
        ld_bias32(accf, lw + L_BF);
#pragma unroll 2
        for (int i = 0; i < 32; ++i) fmarow32(accf, lw + L_WF + i * 32, my[i]);
#pragma unroll
        for (int k = 0; k < 32; ++k) my[k] = accf[k];              // feat -> LDS

        // ---- view layer: 59 -> 32 (+relu): [feat(32), posenc(d)(27)] ----
        float accv[32];
        ld_bias32(accv, lw + L_BV);
#pragma unroll 2
        for (int i = 0; i < 32; ++i) fmarow32(accv, lw + L_WV + i * 32, my[i]);
        fmarow32(accv, lw + L_WV + 32 * 32, dx);
        fmarow32(accv, lw + L_WV + 33 * 32, dy);
        fmarow32(accv, lw + L_WV + 34 * 32, dz);
        {
            float tx = dx, ty = dy, tz = dz;
#pragma unroll 1
            for (int l = 0; l < 4; ++l) {
                const float sx = sinf(tx), cx = cosf(tx);
                const float sy = sinf(ty), cy = cosf(ty);
                const float sz = sinf(tz), cz = cosf(tz);
                const float* r = lw + L_WV + (35 + 6 * l) * 32;
                fmarow32(accv, r + 0 * 32, sx);
                fmarow32(accv, r + 1 * 32, sy);
                fmarow32(accv, r + 2 * 32, sz);
                fmarow32(accv, r + 3 * 32, cx);
                fmarow32(accv, r + 4 * 32, cy);
                fmarow32(accv, r + 5 * 32, cz);
                tx += tx; ty += ty; tz += tz;
            }
        }
#pragma unroll
        for (int k = 0; k < 32; ++k) my[k] = fmaxf(accv[k], 0.f);  // hv -> LDS

        // ---- rgb head: 3 dots over 32 ----
        {
            float r0 = 0.f, r1 = 0.f, r2 = 0.f;
#pragma unroll 4
            for (int i = 0; i < 32; ++i) {
                const float vv = my[i];
                r0 = fmaf(vv, lw[L_WR + i * 3 + 0], r0);
                r1 = fmaf(vv, lw[L_WR + i * 3 + 1], r1);
                r2 = fmaf(vv, lw[L_WR + i * 3 + 2], r2);
            }
            if (live) {
                out_rgb[3 * pt + 0] = r0 + lw[L_BSR + 1];
                out_rgb[3 * pt + 1] = r1 + lw[L_BSR + 2];
                out_rgb[3 * pt + 2] = r2 + lw[L_BSR + 3];
            }
        }
    }
}

extern "C" void kernel_launch(void* const* d_in, const int* in_sizes, int n_in,
                              void* d_out, int out_size, void* d_ws, size_t ws_size,
                              hipStream_t stream) {
    const float* pts      = (const float*)d_in[0];
    const float* viewdirs = (const float*)d_in[1];
    const float* W1   = (const float*)d_in[2];
    const float* b1   = (const float*)d_in[3];
    const float* W2   = (const float*)d_in[4];
    const float* b2   = (const float*)d_in[5];
    const float* Wf   = (const float*)d_in[6];
    const float* bfc  = (const float*)d_in[7];
    const float* Wsig = (const float*)d_in[8];
    const float* bsig = (const float*)d_in[9];
    const float* Wv   = (const float*)d_in[10];
    const float* bv   = (const float*)d_in[11];
    const float* Wrgb = (const float*)d_in[12];
    const float* brgb = (const float*)d_in[13];

    const int n = in_sizes[0] / 3;          // 65536 points
    const int n_rays = in_sizes[1] / 3;     // 1024 rays
    const int samples = n / n_rays;         // 64 samples/ray

    float* out_rgb = (float*)d_out;
    float* out_sigma = out_rgb + (size_t)n * 3;

    int* ws = (int*)d_ws;
    int* counts = ws + WS_COUNTS;
    int* offsets = ws + WS_OFFSETS;
    int* cursor = ws + WS_CURSOR;
    int* order = ws + WS_ORDER;

    hipMemsetAsync(counts, 0, 4096 * sizeof(int), stream);
    hist_kernel<<<(n + 255) / 256, 256, 0, stream>>>(pts, counts, n);
    scan_kernel<<<1, 256, 0, stream>>>(counts, offsets, cursor);
    scatter_kernel<<<(n + 255) / 256, 256, 0, stream>>>(pts, cursor, order, n);
    expert_mlp_kernel<<<4096, 64, 0, stream>>>(
        pts, viewdirs, W1, b1, W2, b2, Wf, bfc, Wsig, bsig, Wv, bv, Wrgb, brgb,
        counts, offsets, order, out_rgb, out_sigma, samples);
}

// Round 8
// 325.017 us; speedup vs baseline: 5.9422x; 1.1336x over previous
//
#include <hip/hip_runtime.h>

// KiloNeRF grouped tiny-MLP — round 12: column decomposition, lane=(half,out).
//
// R11 post-mortem: weights-once FETCH achieved (59MB) but 37.9KB LDS/block ->
// 1 wave/SIMD -> every ds_read->fma dep exposed (VALUBusy 16%, occ 10%).
// R12: wave = expert, 2 points/iter (one per 32-lane half); lane (h,o) owns
// output neuron o of point h as ONE scalar accumulator. Activations broadcast
// via 768B LDS table (uniform-per-half b128 reads); posenc built cooperatively
// (<=3 trig values per lane, not 84 per thread). W2/Wf/heads/biases live in
// REGISTERS as per-lane columns (static full unroll); W1/Wv live in LDS
// (15.6KB, per-lane ds_read_b32, lanes 0..31 -> banks 0..31 conflict-free).
// Heads reduce with 5-step __shfl_xor inside each half. ~130 VGPR, 16.4KB LDS
// -> ~9 blocks/CU (2.25 waves/SIMD) and a ~75%-VALU instruction stream.

// ---- workspace layout (ints) ----
#define WS_COUNTS 0
#define WS_OFFSETS 4096
#define WS_CURSOR 8192
#define WS_ORDER 12288

// ---- LDS weight slab (floats) ----
#define L_W1 0        // [63][32]
#define L_WV 2016     // [59][32]
#define L_TOT 3904    // 15616 B

__device__ __forceinline__ int expert_id(float px, float py, float pz) {
    float nx = (px - (-1.5f)) / 3.0f;
    float ny = (py - (-1.5f)) / 3.0f;
    float nz = (pz - (-1.5f)) / 3.0f;
    float sx = fminf(fmaxf(nx * 16.0f, 0.0f), 15.0f);
    float sy = fminf(fmaxf(ny * 16.0f, 0.0f), 15.0f);
    float sz = fminf(fmaxf(nz * 16.0f, 0.0f), 15.0f);
    return (int)sx * 256 + (int)sy * 16 + (int)sz;
}

// two-phase staging: issue all global loads into regs, then all LDS writes.
template <int N4>
__device__ __forceinline__ void stage4(float* dst, const float* __restrict__ src,
                                       int tid) {
    constexpr int ITER = (N4 + 63) / 64;
    float4 buf[ITER];
#pragma unroll
    for (int j = 0; j < ITER; ++j) {
        const int t = j * 64 + tid;
        if (t < N4) buf[j] = ((const float4*)src)[t];
    }
#pragma unroll
    for (int j = 0; j < ITER; ++j) {
        const int t = j * 64 + tid;
        if (t < N4) ((float4*)dst)[t] = buf[j];
    }
}

// posenc element: idx 0..2 raw coord; idx 3+6l+r: r<3 sin(2^l c[r]) else cos.
__device__ __forceinline__ float enc_val(int idx, float x, float y, float z) {
    if (idx < 3) return (idx == 0) ? x : ((idx == 1) ? y : z);
    const int k = idx - 3;
    const int l = k / 6;
    const int r = k - 6 * l;
    const int c = (r < 3) ? r : r - 3;
    const float cv = (c == 0) ? x : ((c == 1) ? y : z);
    const float a = ldexpf(cv, l);
    return (r < 3) ? sinf(a) : cosf(a);
}

// ---------------- pass A: histogram ----------------
__global__ __launch_bounds__(256) void hist_kernel(const float* __restrict__ pts,
                                                   int* __restrict__ counts, int n) {
    int i = blockIdx.x * 256 + threadIdx.x;
    if (i < n) {
        int e = expert_id(pts[3 * i + 0], pts[3 * i + 1], pts[3 * i + 2]);
        atomicAdd(&counts[e], 1);
    }
}

// ---------------- pass B: exclusive scan of 4096 counts (1 block) ----------
__global__ __launch_bounds__(256) void scan_kernel(const int* __restrict__ counts,
                                                   int* __restrict__ offsets,
                                                   int* __restrict__ cursor) {
    const int tid = threadIdx.x;
    const int lane = tid & 63, wave = tid >> 6;
    const int base = tid * 16;
    int c[16], loc[16], sum = 0;
#pragma unroll
    for (int j = 0; j < 16; ++j) c[j] = counts[base + j];
#pragma unroll
    for (int j = 0; j < 16; ++j) { loc[j] = sum; sum += c[j]; }
    int v = sum;
#pragma unroll
    for (int off = 1; off <= 32; off <<= 1) {
        int u = __shfl_up(v, off, 64);
        if (lane >= off) v += u;
    }
    __shared__ int wtot[4];
    if (lane == 63) wtot[wave] = v;
    __syncthreads();
    int wbase = 0;
    for (int w = 0; w < wave; ++w) wbase += wtot[w];
    const int excl = wbase + v - sum;
#pragma unroll
    for (int j = 0; j < 16; ++j) {
        int o = excl + loc[j];
        offsets[base + j] = o;
        cursor[base + j] = o;
    }
}

// ---------------- pass C: scatter point ids into buckets ----------------
__global__ __launch_bounds__(256) void scatter_kernel(const float* __restrict__ pts,
                                                      int* __restrict__ cursor,
                                                      int* __restrict__ order, int n) {
    int i = blockIdx.x * 256 + threadIdx.x;
    if (i < n) {
        int e = expert_id(pts[3 * i + 0], pts[3 * i + 1], pts[3 * i + 2]);
        int pos = atomicAdd(&cursor[e], 1);
        order[pos] = i;
    }
}

// ---------------- pass D: wave = expert, lane = (point-half, out-neuron) ----
__global__ __launch_bounds__(64) void expert_mlp_kernel(
    const float* __restrict__ pts, const float* __restrict__ viewdirs,
    const float* __restrict__ W1, const float* __restrict__ b1,
    const float* __restrict__ W2, const float* __restrict__ b2,
    const float* __restrict__ Wf, const float* __restrict__ bfc,
    const float* __restrict__ Wsig, const float* __restrict__ bsig,
    const float* __restrict__ Wv, const float* __restrict__ bv,
    const float* __restrict__ Wrgb, const float* __restrict__ brgb,
    const int* __restrict__ counts, const int* __restrict__ offsets,
    const int* __restrict__ order,
    float* __restrict__ out_rgb, float* __restrict__ out_sigma, int samples) {

    const int e = blockIdx.x;
    const int cnt = counts[e];
    if (cnt == 0) return;
    const int start = offsets[e];
    const int lane = threadIdx.x;
    const int h = lane >> 5;       // which point of the pair
    const int o = lane & 31;       // output neuron

    __shared__ float lw[L_TOT];    // W1 + Wv (15.6 KB)
    __shared__ float xs[2][64];    // per-half broadcast table (posenc / acts)
    __shared__ float xd[2][32];    // per-half dir-posenc (27 used)

    // ---- stage W1, Wv into LDS (two-phase, pipelined) ----
    stage4<504>(lw + L_W1, W1 + (size_t)e * 2016, lane);
    stage4<472>(lw + L_WV, Wv + (size_t)e * 1888, lane);

    // ---- per-lane weight columns in registers (static indexing only) ----
    const float* __restrict__ W2e = W2 + (size_t)e * 1024;
    const float* __restrict__ Wfe = Wf + (size_t)e * 1024;
    float w2c[32], wfc[32];
#pragma unroll
    for (int i = 0; i < 32; ++i) w2c[i] = W2e[i * 32 + o];
#pragma unroll
    for (int i = 0; i < 32; ++i) wfc[i] = Wfe[i * 32 + o];
    const float wsg = Wsig[(size_t)e * 32 + o];
    const float wr0 = Wrgb[(size_t)e * 96 + o * 3 + 0];
    const float wr1 = Wrgb[(size_t)e * 96 + o * 3 + 1];
    const float wr2 = Wrgb[(size_t)e * 96 + o * 3 + 2];
    const float b1o = b1[(size_t)e * 32 + o];
    const float b2o = b2[(size_t)e * 32 + o];
    const float bfo = bfc[(size_t)e * 32 + o];
    const float bvo = bv[(size_t)e * 32 + o];
    const float bsg = bsig[e];
    const float br0 = brgb[3 * e + 0];
    const float br1 = brgb[3 * e + 1];
    const float br2 = brgb[3 * e + 2];

    const bool pow2 = (samples & (samples - 1)) == 0;
    const int sh = 31 - __clz(samples);

    for (int s0 = 0; s0 < cnt; s0 += 2) {
        const int s = s0 + h;
        const bool live = (s < cnt);
        const int pt = order[start + (live ? s : (cnt - 1))];

        const float px = pts[3 * pt + 0];
        const float py = pts[3 * pt + 1];
        const float pz = pts[3 * pt + 2];
        const int ray = pow2 ? (pt >> sh) : (pt / samples);
        const float dx = viewdirs[3 * ray + 0];
        const float dy = viewdirs[3 * ray + 1];
        const float dz = viewdirs[3 * ray + 2];

        // ---- build posenc tables cooperatively (<=3 trig values per lane) ----
        xs[h][o] = enc_val(o, px, py, pz);
        if (o < 31) xs[h][o + 32] = enc_val(o + 32, px, py, pz);
        if (o < 27) xd[h][o] = enc_val(o, dx, dy, dz);
        // single wave: same-wave DS ops complete in program order, no barrier

        // ---- layer 1: out1[o] = b1[o] + sum_i x[i] * W1[i][o] ----
        float a1 = b1o;
#pragma unroll
        for (int q = 0; q < 15; ++q) {
            const float4 xq = *(const float4*)&xs[h][4 * q];
            a1 = fmaf(xq.x, lw[L_W1 + (4 * q + 0) * 32 + o], a1);
            a1 = fmaf(xq.y, lw[L_W1 + (4 * q + 1) * 32 + o], a1);
            a1 = fmaf(xq.z, lw[L_W1 + (4 * q + 2) * 32 + o], a1);
            a1 = fmaf(xq.w, lw[L_W1 + (4 * q + 3) * 32 + o], a1);
        }
        a1 = fmaf(xs[h][60], lw[L_W1 + 60 * 32 + o], a1);
        a1 = fmaf(xs[h][61], lw[L_W1 + 61 * 32 + o], a1);
        a1 = fmaf(xs[h][62], lw[L_W1 + 62 * 32 + o], a1);
        const float h1 = fmaxf(a1, 0.f);
        xs[h][o] = h1;                       // publish h (program order)

        // ---- layer 2: register columns, broadcast activations ----
        float a2 = b2o;
#pragma unroll
        for (int q = 0; q < 8; ++q) {
            const float4 xq = *(const float4*)&xs[h][4 * q];
            a2 = fmaf(xq.x, w2c[4 * q + 0], a2);
            a2 = fmaf(xq.y, w2c[4 * q + 1], a2);
            a2 = fmaf(xq.z, w2c[4 * q + 2], a2);
            a2 = fmaf(xq.w, w2c[4 * q + 3], a2);
        }
        const float g = fmaxf(a2, 0.f);

        // ---- sigma head: xor-tree reduce of g*wsig within the half ----
        {
            float sp = g * wsg;
            sp += __shfl_xor(sp, 1, 64);
            sp += __shfl_xor(sp, 2, 64);
            sp += __shfl_xor(sp, 4, 64);
            sp += __shfl_xor(sp, 8, 64);
            sp += __shfl_xor(sp, 16, 64);
            if (live && o == 0) out_sigma[pt] = sp + bsg;
        }
        xs[h][o] = g;                        // publish g

        // ---- feat: 32 -> 32, no relu ----
        float af = bfo;
#pragma unroll
        for (int q = 0; q < 8; ++q) {
            const float4 xq = *(const float4*)&xs[h][4 * q];
            af = fmaf(xq.x, wfc[4 * q + 0], af);
            af = fmaf(xq.y, wfc[4 * q + 1], af);
            af = fmaf(xq.z, wfc[4 * q + 2], af);
            af = fmaf(xq.w, wfc[4 * q + 3], af);
        }
        xs[h][o] = af;                       // publish feat

        // ---- view layer: bv + feat·Wv[0:32] + xd·Wv[32:59] ----
        float av = bvo;
#pragma unroll
        for (int q = 0; q < 8; ++q) {
            const float4 xq = *(const float4*)&xs[h][4 * q];
            av = fmaf(xq.x, lw[L_WV + (4 * q + 0) * 32 + o], av);
            av = fmaf(xq.y, lw[L_WV + (4 * q + 1) * 32 + o], av);
            av = fmaf(xq.z, lw[L_WV + (4 * q + 2) * 32 + o], av);
            av = fmaf(xq.w, lw[L_WV + (4 * q + 3) * 32 + o], av);
        }
#pragma unroll
        for (int q = 0; q < 6; ++q) {
            const float4 xq = *(const float4*)&xd[h][4 * q];
            av = fmaf(xq.x, lw[L_WV + (32 + 4 * q + 0) * 32 + o], av);
            av = fmaf(xq.y, lw[L_WV + (32 + 4 * q + 1) * 32 + o], av);
            av = fmaf(xq.z, lw[L_WV + (32 + 4 * q + 2) * 32 + o], av);
            av = fmaf(xq.w, lw[L_WV + (32 + 4 * q + 3) * 32 + o], av);
        }
        av = fmaf(xd[h][24], lw[L_WV + 56 * 32 + o], av);
        av = fmaf(xd[h][25], lw[L_WV + 57 * 32 + o], av);
        av = fmaf(xd[h][26], lw[L_WV + 58 * 32 + o], av);
        const float hv = fmaxf(av, 0.f);

        // ---- rgb head: 3 xor-tree reductions within the half ----
        {
            float r0 = hv * wr0, r1 = hv * wr1, r2 = hv * wr2;
#pragma unroll
            for (int m = 1; m <= 16; m <<= 1) {
                r0 += __shfl_xor(r0, m, 64);
                r1 += __shfl_xor(r1, m, 64);
                r2 += __shfl_xor(r2, m, 64);
            }
            if (live && o == 0) {
                out_rgb[3 * pt + 0] = r0 + br0;
                out_rgb[3 * pt + 1] = r1 + br1;
                out_rgb[3 * pt + 2] = r2 + br2;
            }
        }
    }
}

extern "C" void kernel_launch(void* const* d_in, const int* in_sizes, int n_in,
                              void* d_out, int out_size, void* d_ws, size_t ws_size,
                              hipStream_t stream) {
    const float* pts      = (const float*)d_in[0];
    const float* viewdirs = (const float*)d_in[1];
    const float* W1   = (const float*)d_in[2];
    const float* b1   = (const float*)d_in[3];
    const float* W2   = (const float*)d_in[4];
    const float* b2   = (const float*)d_in[5];
    const float* Wf   = (const float*)d_in[6];
    const float* bfc  = (const float*)d_in[7];
    const float* Wsig = (const float*)d_in[8];
    const float* bsig = (const float*)d_in[9];
    const float* Wv   = (const float*)d_in[10];
    const float* bv   = (const float*)d_in[11];
    const float* Wrgb = (const float*)d_in[12];
    const float* brgb = (const float*)d_in[13];

    const int n = in_sizes[0] / 3;          // 65536 points
    const int n_rays = in_sizes[1] / 3;     // 1024 rays
    const int samples = n / n_rays;         // 64 samples/ray

    float* out_rgb = (float*)d_out;
    float* out_sigma = out_rgb + (size_t)n * 3;

    int* ws = (int*)d_ws;
    int* counts = ws + WS_COUNTS;
    int* offsets = ws + WS_OFFSETS;
    int* cursor = ws + WS_CURSOR;
    int* order = ws + WS_ORDER;

    hipMemsetAsync(counts, 0, 4096 * sizeof(int), stream);
    hist_kernel<<<(n + 255) / 256, 256, 0, stream>>>(pts, counts, n);
    scan_kernel<<<1, 256, 0, stream>>>(counts, offsets, cursor);
    scatter_kernel<<<(n + 255) / 256, 256, 0, stream>>>(pts, cursor, order, n);
    expert_mlp_kernel<<<4096, 64, 0, stream>>>(
        pts, viewdirs, W1, b1, W2, b2, Wf, bfc, Wsig, bsig, Wv, bv, Wrgb, brgb,
        counts, offsets, order, out_rgb, out_sigma, samples);
}

// Round 9
// 258.158 us; speedup vs baseline: 7.4812x; 1.2590x over previous
//
#include <hip/hip_runtime.h>

// KiloNeRF grouped tiny-MLP — round 13: 4-wave shared-slab, 2 points/lane.
//
// R12 post-mortem: WRITE 58MB = w2c/wfc per-lane weight ARRAYS spilled to
// scratch at init (VGPR capped at 96); VALUBusy 12% / occ 11% = serial FMA
// chain at ~1 wave/SIMD. R13: block = expert, 256 threads (4 waves) sharing
// ONE 24.8KB LDS weight slab (staged 256-wide, one __syncthreads). Column
// decomposition kept: lane=(half,out-neuron), weights as conflict-free
// per-lane ds_read_b32 (lanes 0..31 -> banks 0..31, halves broadcast-dup).
// Each wave does 4 points/iter (2 per lane): one weight register feeds 2
// fmas (A/B points) -> half the weight reads per point + 2-way ILP on the
// accumulator chains. NO per-lane weight arrays -> nothing to spill. Heads +
// biases are per-lane scalars from LDS. 31KB LDS -> 5 blocks/CU = 20
// waves/CU. Same-wave DS program order within a wave; one barrier total.

// ---- workspace layout (ints) ----
#define WS_COUNTS 0
#define WS_OFFSETS 4096
#define WS_CURSOR 8192
#define WS_ORDER 12288

// ---- LDS weight slab offsets (floats, all 16B-aligned) ----
#define L_W1 0        // [63][32]
#define L_W2 2016     // [32][32]
#define L_WF 3040     // [32][32]
#define L_WV 4064     // [59][32]
#define L_WS 5952     // [32]
#define L_WR 5984     // [32][3]
#define L_B1 6080
#define L_B2 6112
#define L_BF 6144
#define L_BV 6176
#define L_BSR 6208    // [0]=bsig, [1..3]=brgb
#define L_TOT 6212

__device__ __forceinline__ int expert_id(float px, float py, float pz) {
    float nx = (px - (-1.5f)) / 3.0f;
    float ny = (py - (-1.5f)) / 3.0f;
    float nz = (pz - (-1.5f)) / 3.0f;
    float sx = fminf(fmaxf(nx * 16.0f, 0.0f), 15.0f);
    float sy = fminf(fmaxf(ny * 16.0f, 0.0f), 15.0f);
    float sz = fminf(fmaxf(nz * 16.0f, 0.0f), 15.0f);
    return (int)sx * 256 + (int)sy * 16 + (int)sz;
}

// two-phase staging, 256 threads: issue all global loads, then all LDS writes.
template <int N4>
__device__ __forceinline__ void stage256(float* dst, const float* __restrict__ src,
                                         int tid) {
    constexpr int ITER = (N4 + 255) / 256;
    float4 buf[ITER];
#pragma unroll
    for (int j = 0; j < ITER; ++j) {
        const int t = j * 256 + tid;
        if (t < N4) buf[j] = ((const float4*)src)[t];
    }
#pragma unroll
    for (int j = 0; j < ITER; ++j) {
        const int t = j * 256 + tid;
        if (t < N4) ((float4*)dst)[t] = buf[j];
    }
}

// posenc element: idx 0..2 raw coord; idx 3+6l+r: r<3 sin(2^l c[r]) else cos.
__device__ __forceinline__ float enc_val(int idx, float x, float y, float z) {
    if (idx < 3) return (idx == 0) ? x : ((idx == 1) ? y : z);
    const int k = idx - 3;
    const int l = k / 6;
    const int r = k - 6 * l;
    const int c = (r < 3) ? r : r - 3;
    const float cv = (c == 0) ? x : ((c == 1) ? y : z);
    const float a = ldexpf(cv, l);      // exact 2^l * x, matches reference
    return (r < 3) ? sinf(a) : cosf(a);
}

// ---------------- pass A: histogram ----------------
__global__ __launch_bounds__(256) void hist_kernel(const float* __restrict__ pts,
                                                   int* __restrict__ counts, int n) {
    int i = blockIdx.x * 256 + threadIdx.x;
    if (i < n) {
        int e = expert_id(pts[3 * i + 0], pts[3 * i + 1], pts[3 * i + 2]);
        atomicAdd(&counts[e], 1);
    }
}

// ---------------- pass B: exclusive scan of 4096 counts (1 block) ----------
__global__ __launch_bounds__(256) void scan_kernel(const int* __restrict__ counts,
                                                   int* __restrict__ offsets,
                                                   int* __restrict__ cursor) {
    const int tid = threadIdx.x;
    const int lane = tid & 63, wave = tid >> 6;
    const int base = tid * 16;
    int c[16], loc[16], sum = 0;
#pragma unroll
    for (int j = 0; j < 16; ++j) c[j] = counts[base + j];
#pragma unroll
    for (int j = 0; j < 16; ++j) { loc[j] = sum; sum += c[j]; }
    int v = sum;
#pragma unroll
    for (int off = 1; off <= 32; off <<= 1) {
        int u = __shfl_up(v, off, 64);
        if (lane >= off) v += u;
    }
    __shared__ int wtot[4];
    if (lane == 63) wtot[wave] = v;
    __syncthreads();
    int wbase = 0;
    for (int w = 0; w < wave; ++w) wbase += wtot[w];
    const int excl = wbase + v - sum;
#pragma unroll
    for (int j = 0; j < 16; ++j) {
        int o = excl + loc[j];
        offsets[base + j] = o;
        cursor[base + j] = o;
    }
}

// ---------------- pass C: scatter point ids into buckets ----------------
__global__ __launch_bounds__(256) void scatter_kernel(const float* __restrict__ pts,
                                                      int* __restrict__ cursor,
                                                      int* __restrict__ order, int n) {
    int i = blockIdx.x * 256 + threadIdx.x;
    if (i < n) {
        int e = expert_id(pts[3 * i + 0], pts[3 * i + 1], pts[3 * i + 2]);
        int pos = atomicAdd(&cursor[e], 1);
        order[pos] = i;
    }
}

// ------- pass D: block = expert (4 waves share slab), 4 pts/wave-iter -------
__global__ __launch_bounds__(256) void expert_mlp_kernel(
    const float* __restrict__ pts, const float* __restrict__ viewdirs,
    const float* __restrict__ W1, const float* __restrict__ b1,
    const float* __restrict__ W2, const float* __restrict__ b2,
    const float* __restrict__ Wf, const float* __restrict__ bfc,
    const float* __restrict__ Wsig, const float* __restrict__ bsig,
    const float* __restrict__ Wv, const float* __restrict__ bv,
    const float* __restrict__ Wrgb, const float* __restrict__ brgb,
    const int* __restrict__ counts, const int* __restrict__ offsets,
    const int* __restrict__ order,
    float* __restrict__ out_rgb, float* __restrict__ out_sigma, int samples) {

    const int e = blockIdx.x;
    const int cnt = counts[e];
    if (cnt == 0) return;                 // uniform: whole block exits
    const int start = offsets[e];
    const int tid = threadIdx.x;
    const int wave = tid >> 6;
    const int lane = tid & 63;
    const int h = lane >> 5;              // half: which of the pair
    const int o = lane & 31;              // output neuron

    __shared__ float lw[L_TOT];           // 24.8 KB weight slab
    __shared__ float xs[4][4][64];        // [wave][point][dim] broadcast table
    __shared__ float xd[4][4][32];        // [wave][point][dir-dim]

    // ---- stage the expert's full slab (two-phase, 256-wide) ----
    stage256<504>(lw + L_W1, W1 + (size_t)e * 2016, tid);
    stage256<256>(lw + L_W2, W2 + (size_t)e * 1024, tid);
    stage256<256>(lw + L_WF, Wf + (size_t)e * 1024, tid);
    stage256<472>(lw + L_WV, Wv + (size_t)e * 1888, tid);
    stage256<8>(lw + L_WS, Wsig + (size_t)e * 32, tid);
    stage256<24>(lw + L_WR, Wrgb + (size_t)e * 96, tid);
    stage256<8>(lw + L_B1, b1 + (size_t)e * 32, tid);
    stage256<8>(lw + L_B2, b2 + (size_t)e * 32, tid);
    stage256<8>(lw + L_BF, bfc + (size_t)e * 32, tid);
    stage256<8>(lw + L_BV, bv + (size_t)e * 32, tid);
    if (tid == 0) lw[L_BSR] = bsig[e];
    if (tid < 3) lw[L_BSR + 1 + tid] = brgb[3 * e + tid];
    __syncthreads();                      // the only barrier

    // ---- per-lane scalars (no arrays -> nothing can spill) ----
    const float b1o = lw[L_B1 + o];
    const float b2o = lw[L_B2 + o];
    const float bfo = lw[L_BF + o];
    const float bvo = lw[L_BV + o];
    const float wsg = lw[L_WS + o];
    const float wr0 = lw[L_WR + 3 * o + 0];
    const float wr1 = lw[L_WR + 3 * o + 1];
    const float wr2 = lw[L_WR + 3 * o + 2];
    const float bsg = lw[L_BSR];
    const float br0 = lw[L_BSR + 1], br1 = lw[L_BSR + 2], br2 = lw[L_BSR + 3];

    float* xsA = xs[wave][h];     float* xsB = xs[wave][2 + h];
    float* xdA = xd[wave][h];     float* xdB = xd[wave][2 + h];

    const bool pow2 = (samples & (samples - 1)) == 0;
    const int sh = 31 - __clz(samples);

    for (int s0 = 4 * wave; s0 < cnt; s0 += 16) {
        const int sA = s0 + h, sB = s0 + 2 + h;
        const bool liveA = (sA < cnt), liveB = (sB < cnt);
        const int ptA = order[start + (liveA ? sA : cnt - 1)];
        const int ptB = order[start + (liveB ? sB : cnt - 1)];

        const float pxA = pts[3 * ptA + 0], pyA = pts[3 * ptA + 1], pzA = pts[3 * ptA + 2];
        const float pxB = pts[3 * ptB + 0], pyB = pts[3 * ptB + 1], pzB = pts[3 * ptB + 2];
        const int rayA = pow2 ? (ptA >> sh) : (ptA / samples);
        const int rayB = pow2 ? (ptB >> sh) : (ptB / samples);
        const float dxA = viewdirs[3 * rayA + 0], dyA = viewdirs[3 * rayA + 1], dzA = viewdirs[3 * rayA + 2];
        const float dxB = viewdirs[3 * rayB + 0], dyB = viewdirs[3 * rayB + 1], dzB = viewdirs[3 * rayB + 2];

        // ---- cooperative posenc: <=6 trig evals per lane ----
        xsA[o] = enc_val(o, pxA, pyA, pzA);
        xsB[o] = enc_val(o, pxB, pyB, pzB);
        if (o < 31) {
            xsA[o + 32] = enc_val(o + 32, pxA, pyA, pzA);
            xsB[o + 32] = enc_val(o + 32, pxB, pyB, pzB);
        }
        if (o < 27) {
            xdA[o] = enc_val(o, dxA, dyA, dzA);
            xdB[o] = enc_val(o, dxB, dyB, dzB);
        }
        // same wave: DS ops in program order -> no barrier

        // ---- layer 1: 63 -> 32; shared weight regs feed both points ----
        float aA = b1o, aB = b1o;
#pragma unroll
        for (int q = 0; q < 15; ++q) {
            const float w0 = lw[L_W1 + (4 * q + 0) * 32 + o];
            const float w1 = lw[L_W1 + (4 * q + 1) * 32 + o];
            const float w2 = lw[L_W1 + (4 * q + 2) * 32 + o];
            const float w3 = lw[L_W1 + (4 * q + 3) * 32 + o];
            const float4 xA = *(const float4*)&xsA[4 * q];
            const float4 xB = *(const float4*)&xsB[4 * q];
            aA = fmaf(xA.x, w0, aA); aB = fmaf(xB.x, w0, aB);
            aA = fmaf(xA.y, w1, aA); aB = fmaf(xB.y, w1, aB);
            aA = fmaf(xA.z, w2, aA); aB = fmaf(xB.z, w2, aB);
            aA = fmaf(xA.w, w3, aA); aB = fmaf(xB.w, w3, aB);
        }
#pragma unroll
        for (int i = 60; i < 63; ++i) {
            const float w = lw[L_W1 + i * 32 + o];
            aA = fmaf(xsA[i], w, aA); aB = fmaf(xsB[i], w, aB);
        }
        xsA[o] = fmaxf(aA, 0.f);           // publish h1
        xsB[o] = fmaxf(aB, 0.f);

        // ---- layer 2: 32 -> 32 ----
        aA = b2o; aB = b2o;
#pragma unroll
        for (int q = 0; q < 8; ++q) {
            const float w0 = lw[L_W2 + (4 * q + 0) * 32 + o];
            const float w1 = lw[L_W2 + (4 * q + 1) * 32 + o];
            const float w2 = lw[L_W2 + (4 * q + 2) * 32 + o];
            const float w3 = lw[L_W2 + (4 * q + 3) * 32 + o];
            const float4 xA = *(const float4*)&xsA[4 * q];
            const float4 xB = *(const float4*)&xsB[4 * q];
            aA = fmaf(xA.x, w0, aA); aB = fmaf(xB.x, w0, aB);
            aA = fmaf(xA.y, w1, aA); aB = fmaf(xB.y, w1, aB);
            aA = fmaf(xA.z, w2, aA); aB = fmaf(xB.z, w2, aB);
            aA = fmaf(xA.w, w3, aA); aB = fmaf(xB.w, w3, aB);
        }
        const float gA = fmaxf(aA, 0.f), gB = fmaxf(aB, 0.f);

        // ---- sigma head: xor-tree within each half, both points ----
        {
            float spA = gA * wsg, spB = gB * wsg;
#pragma unroll
            for (int m = 1; m <= 16; m <<= 1) {
                spA += __shfl_xor(spA, m, 64);
                spB += __shfl_xor(spB, m, 64);
            }
            if (liveA && o == 0) out_sigma[ptA] = spA + bsg;
            if (liveB && o == 0) out_sigma[ptB] = spB + bsg;
        }
        xsA[o] = gA;                        // publish g
        xsB[o] = gB;

        // ---- feat: 32 -> 32, no relu ----
        aA = bfo; aB = bfo;
#pragma unroll
        for (int q = 0; q < 8; ++q) {
            const float w0 = lw[L_WF + (4 * q + 0) * 32 + o];
            const float w1 = lw[L_WF + (4 * q + 1) * 32 + o];
            const float w2 = lw[L_WF + (4 * q + 2) * 32 + o];
            const float w3 = lw[L_WF + (4 * q + 3) * 32 + o];
            const float4 xA = *(const float4*)&xsA[4 * q];
            const float4 xB = *(const float4*)&xsB[4 * q];
            aA = fmaf(xA.x, w0, aA); aB = fmaf(xB.x, w0, aB);
            aA = fmaf(xA.y, w1, aA); aB = fmaf(xB.y, w1, aB);
            aA = fmaf(xA.z, w2, aA); aB = fmaf(xB.z, w2, aB);
            aA = fmaf(xA.w, w3, aA); aB = fmaf(xB.w, w3, aB);
        }
        xsA[o] = aA;                        // publish feat
        xsB[o] = aB;

        // ---- view layer: 59 -> 32 (+relu): [feat(32), posenc(d)(27)] ----
        float avA = bvo, avB = bvo;
#pragma unroll
        for (int q = 0; q < 8; ++q) {
            const float w0 = lw[L_WV + (4 * q + 0) * 32 + o];
            const float w1 = lw[L_WV + (4 * q + 1) * 32 + o];
            const float w2 = lw[L_WV + (4 * q + 2) * 32 + o];
            const float w3 = lw[L_WV + (4 * q + 3) * 32 + o];
            const float4 xA = *(const float4*)&xsA[4 * q];
            const float4 xB = *(const float4*)&xsB[4 * q];
            avA = fmaf(xA.x, w0, avA); avB = fmaf(xB.x, w0, avB);
            avA = fmaf(xA.y, w1, avA); avB = fmaf(xB.y, w1, avB);
            avA = fmaf(xA.z, w2, avA); avB = fmaf(xB.z, w2, avB);
            avA = fmaf(xA.w, w3, avA); avB = fmaf(xB.w, w3, avB);
        }
#pragma unroll
        for (int q = 0; q < 6; ++q) {
            const float w0 = lw[L_WV + (32 + 4 * q + 0) * 32 + o];
            const float w1 = lw[L_WV + (32 + 4 * q + 1) * 32 + o];
            const float w2 = lw[L_WV + (32 + 4 * q + 2) * 32 + o];
            const float w3 = lw[L_WV + (32 + 4 * q + 3) * 32 + o];
            const float4 xA = *(const float4*)&xdA[4 * q];
            const float4 xB = *(const float4*)&xdB[4 * q];
            avA = fmaf(xA.x, w0, avA); avB = fmaf(xB.x, w0, avB);
            avA = fmaf(xA.y, w1, avA); avB = fmaf(xB.y, w1, avB);
            avA = fmaf(xA.z, w2, avA); avB = fmaf(xB.z, w2, avB);
            avA = fmaf(xA.w, w3, avA); avB = fmaf(xB.w, w3, avB);
        }
#pragma unroll
        for (int i = 24; i < 27; ++i) {
            const float w = lw[L_WV + (32 + i) * 32 + o];
            avA = fmaf(xdA[i], w, avA); avB = fmaf(xdB[i], w, avB);
        }
        const float hvA = fmaxf(avA, 0.f), hvB = fmaxf(avB, 0.f);

        // ---- rgb head: 3 xor-tree reductions per point ----
        {
            float r0A = hvA * wr0, r1A = hvA * wr1, r2A = hvA * wr2;
            float r0B = hvB * wr0, r1B = hvB * wr1, r2B = hvB * wr2;
#pragma unroll
            for (int m = 1; m <= 16; m <<= 1) {
                r0A += __shfl_xor(r0A, m, 64);
                r1A += __shfl_xor(r1A, m, 64);
                r2A += __shfl_xor(r2A, m, 64);
                r0B += __shfl_xor(r0B, m, 64);
                r1B += __shfl_xor(r1B, m, 64);
                r2B += __shfl_xor(r2B, m, 64);
            }
            if (liveA && o == 0) {
                out_rgb[3 * ptA + 0] = r0A + br0;
                out_rgb[3 * ptA + 1] = r1A + br1;
                out_rgb[3 * ptA + 2] = r2A + br2;
            }
            if (liveB && o == 0) {
                out_rgb[3 * ptB + 0] = r0B + br0;
                out_rgb[3 * ptB + 1] = r1B + br1;
                out_rgb[3 * ptB + 2] = r2B + br2;
            }
        }
    }
}

extern "C" void kernel_launch(void* const* d_in, const int* in_sizes, int n_in,
                              void* d_out, int out_size, void* d_ws, size_t ws_size,
                              hipStream_t stream) {
    const float* pts      = (const float*)d_in[0];
    const float* viewdirs = (const float*)d_in[1];
    const float* W1   = (const float*)d_in[2];
    const float* b1   = (const float*)d_in[3];
    const float* W2   = (const float*)d_in[4];
    const float* b2   = (const float*)d_in[5];
    const float* Wf   = (const float*)d_in[6];
    const float* bfc  = (const float*)d_in[7];
    const float* Wsig = (const float*)d_in[8];
    const float* bsig = (const float*)d_in[9];
    const float* Wv   = (const float*)d_in[10];
    const float* bv   = (const float*)d_in[11];
    const float* Wrgb = (const float*)d_in[12];
    const float* brgb = (const float*)d_in[13];

    const int n = in_sizes[0] / 3;          // 65536 points
    const int n_rays = in_sizes[1] / 3;     // 1024 rays
    const int samples = n / n_rays;         // 64 samples/ray

    float* out_rgb = (float*)d_out;
    float* out_sigma = out_rgb + (size_t)n * 3;

    int* ws = (int*)d_ws;
    int* counts = ws + WS_COUNTS;
    int* offsets = ws + WS_OFFSETS;
    int* cursor = ws + WS_CURSOR;
    int* order = ws + WS_ORDER;

    hipMemsetAsync(counts, 0, 4096 * sizeof(int), stream);
    hist_kernel<<<(n + 255) / 256, 256, 0, stream>>>(pts, counts, n);
    scan_kernel<<<1, 256, 0, stream>>>(counts, offsets, cursor);
    scatter_kernel<<<(n + 255) / 256, 256, 0, stream>>>(pts, cursor, order, n);
    expert_mlp_kernel<<<4096, 256, 0, stream>>>(
        pts, viewdirs, W1, b1, W2, b2, Wf, bfc, Wsig, bsig, Wv, bv, Wrgb, brgb,
        counts, offsets, order, out_rgb, out_sigma, samples);
}